// Round 3
// baseline (228.205 us; speedup 1.0000x reference)
//
#include <hip/hip_runtime.h>
#include <math.h>

#define NROWS 16384   // B*T
#define DDIM  2048
#define NEXP  16
#define RBLOCKS 1024  // router grid: 16 rows/block, 4 blocks/CU, fully resident
#define WPB 4         // waves per 256-thread block
#define ZN (RBLOCKS * WPB)

__device__ __forceinline__ float fnoise(float x) {
    return copysignf(sqrtf(fabsf(x)), x);
}

// ws layout (float idx):
//   [0, 32768)       w_noisy [E][D]
//   [32768, 32784)   b_noisy [E]
//   [32800, 36896)   zpartial [ZN] (one float per wave)

__global__ void prep_kernel(const float* __restrict__ weight,
                            const float* __restrict__ sigma_weight,
                            const float* __restrict__ bias,
                            const float* __restrict__ sigma_bias,
                            const float* __restrict__ eps_in,
                            const float* __restrict__ eps_out,
                            float* __restrict__ w_noisy,
                            float* __restrict__ b_noisy) {
    int idx = blockIdx.x * blockDim.x + threadIdx.x;   // 0 .. E*D-1
    int e = idx >> 11;          // / DDIM
    int d = idx & (DDIM - 1);
    float fi = fnoise(eps_in[d]);
    float fo = fnoise(eps_out[e]);
    w_noisy[idx] = weight[idx] + sigma_weight[idx] * fo * fi;
    if (idx < NEXP) {
        b_noisy[idx] = bias[idx] + sigma_bias[idx] * fnoise(eps_out[idx]);
    }
}

// Block: 256 threads = 4 waves; wave wv owns 4 rows. D split in 8 chunks of
// 256 cols. Per chunk: one barrier; w double-buffered in LDS (2x16 KiB); x
// for chunk c+1 prefetched into registers at the top of chunk c. Every wave
// keeps ~8 KiB of global loads in flight at all times -> memory-level
// parallelism to saturate HBM despite ~900-cycle latency.
__global__ __launch_bounds__(256, 4) void router_kernel(
        const float* __restrict__ x,        // [NROWS][DDIM]
        const float* __restrict__ w_noisy,  // [E][D]
        const float* __restrict__ b_noisy,  // [E]
        float* __restrict__ out_router,     // [NROWS][E]
        float* __restrict__ out_idx,        // [NROWS][2] stored as float
        float* __restrict__ zpart) {        // [ZN]
    __shared__ float4 wlds[2][NEXP * 64];   // 2 x 16 KiB: [16][64] float4

    const int tid  = threadIdx.x;
    const int wv   = tid >> 6;
    const int lane = tid & 63;

    const int rowBase = blockIdx.x * 16 + wv * 4;
    const float4* xr0 = (const float4*)(x + (size_t)(rowBase + 0) * DDIM);
    const float4* xr1 = (const float4*)(x + (size_t)(rowBase + 1) * DDIM);
    const float4* xr2 = (const float4*)(x + (size_t)(rowBase + 2) * DDIM);
    const float4* xr3 = (const float4*)(x + (size_t)(rowBase + 3) * DDIM);
    const float4* wsrc = (const float4*)w_noisy;  // [16][512] float4

    float acc[64];
    #pragma unroll
    for (int i = 0; i < 64; ++i) acc[i] = 0.0f;

    float4 xA[4], xB[4], wt[4];

    // ---- prologue: x chunk 0 -> xA, w chunk 0 -> wlds[0]
    xA[0] = xr0[lane]; xA[1] = xr1[lane]; xA[2] = xr2[lane]; xA[3] = xr3[lane];
    #pragma unroll
    for (int j = 0; j < 4; ++j) {
        int f = j * 256 + tid;
        wt[j] = wsrc[(f >> 6) * 512 + (f & 63)];
    }
    #pragma unroll
    for (int j = 0; j < 4; ++j) wlds[0][j * 256 + tid] = wt[j];
    __syncthreads();

    // One pipelined chunk step. c is a compile-time constant at each call.
    auto chunk_step = [&](int c, float4 (&xc)[4], float4 (&xn)[4],
                          const float4* __restrict__ wcur,
                          float4* __restrict__ wnxt) {
        if (c < 7) {
            // issue x prefetch for chunk c+1 (consumed next step)
            int p = (c + 1) * 64 + lane;
            xn[0] = xr0[p]; xn[1] = xr1[p]; xn[2] = xr2[p]; xn[3] = xr3[p];
            // issue w global loads for chunk c+1 (ds-written after compute)
            #pragma unroll
            for (int j = 0; j < 4; ++j) {
                int f = j * 256 + tid;
                wt[j] = wsrc[(f >> 6) * 512 + (c + 1) * 64 + (f & 63)];
            }
        }
        #pragma unroll
        for (int e = 0; e < 16; ++e) {
            float4 w = wcur[e * 64 + lane];
            float s0 = acc[0 * 16 + e];
            float s1 = acc[1 * 16 + e];
            float s2 = acc[2 * 16 + e];
            float s3 = acc[3 * 16 + e];
            s0 = fmaf(xc[0].x, w.x, s0); s0 = fmaf(xc[0].y, w.y, s0);
            s0 = fmaf(xc[0].z, w.z, s0); s0 = fmaf(xc[0].w, w.w, s0);
            s1 = fmaf(xc[1].x, w.x, s1); s1 = fmaf(xc[1].y, w.y, s1);
            s1 = fmaf(xc[1].z, w.z, s1); s1 = fmaf(xc[1].w, w.w, s1);
            s2 = fmaf(xc[2].x, w.x, s2); s2 = fmaf(xc[2].y, w.y, s2);
            s2 = fmaf(xc[2].z, w.z, s2); s2 = fmaf(xc[2].w, w.w, s2);
            s3 = fmaf(xc[3].x, w.x, s3); s3 = fmaf(xc[3].y, w.y, s3);
            s3 = fmaf(xc[3].z, w.z, s3); s3 = fmaf(xc[3].w, w.w, s3);
            acc[0 * 16 + e] = s0;
            acc[1 * 16 + e] = s1;
            acc[2 * 16 + e] = s2;
            acc[3 * 16 + e] = s3;
        }
        if (c < 7) {
            // land staged w into the other buffer (vmcnt wait overlapped
            // with the FMA block above), then one barrier per chunk
            #pragma unroll
            for (int j = 0; j < 4; ++j) wnxt[j * 256 + tid] = wt[j];
            __syncthreads();
        }
    };

    chunk_step(0, xA, xB, wlds[0], wlds[1]);
    chunk_step(1, xB, xA, wlds[1], wlds[0]);
    chunk_step(2, xA, xB, wlds[0], wlds[1]);
    chunk_step(3, xB, xA, wlds[1], wlds[0]);
    chunk_step(4, xA, xB, wlds[0], wlds[1]);
    chunk_step(5, xB, xA, wlds[1], wlds[0]);
    chunk_step(6, xA, xB, wlds[0], wlds[1]);
    chunk_step(7, xB, xA, wlds[1], wlds[0]);

    // Butterfly transpose-reduce: lane l ends with full sum of index l
    // (l = r*16 + e over this wave's 4 rows x 16 experts).
    #pragma unroll
    for (int half = 32; half >= 1; half >>= 1) {
        #pragma unroll
        for (int i = 0; i < half; ++i) {
            bool hi = (lane & half) != 0;
            float keep = hi ? acc[i + half] : acc[i];
            float send = hi ? acc[i] : acc[i + half];
            float recv = __shfl_xor(send, half, 64);
            acc[i] = keep + recv;
        }
    }

    const int e = lane & 15;           // expert owned by this lane
    const int r = lane >> 4;           // local row 0..3
    const int row = rowBase + r;
    float logit = acc[0] + b_noisy[e];

    // top-1 with lower-index tie-break within the 16-lane group
    float m1 = logit; int i1 = e;
    #pragma unroll
    for (int off = 8; off >= 1; off >>= 1) {
        float om = __shfl_xor(m1, off, 64);
        int   oi = __shfl_xor(i1, off, 64);
        if (om > m1 || (om == m1 && oi < i1)) { m1 = om; i1 = oi; }
    }
    // top-2: mask out i1
    float v2 = (e == i1) ? -3.4e38f : logit;
    float m2 = v2; int i2 = e;
    #pragma unroll
    for (int off = 8; off >= 1; off >>= 1) {
        float om = __shfl_xor(m2, off, 64);
        int   oi = __shfl_xor(i2, off, 64);
        if (om > m2 || (om == m2 && oi < i2)) { m2 = om; i2 = oi; }
    }

    // softmax over sparse logits: exp(-1e30 - m1) == 0 exactly, so only
    // positions i1, i2 are nonzero.
    float t = expf(m2 - m1);
    float p1 = 1.0f / (1.0f + t);
    float val = (e == i1) ? p1 : ((e == i2) ? t * p1 : 0.0f);
    out_router[(size_t)rowBase * NEXP + lane] = val;   // fully coalesced

    if (e < 2) {
        out_idx[(size_t)row * 2 + e] = (float)((e == 0) ? i1 : i2);
    }

    // z-loss partial: sum lse^2 over this wave's 4 rows, no atomics.
    float zv = 0.0f;
    if (e == 0) {
        float lse = m1 + log1pf(t);
        zv = lse * lse;
    }
    zv += __shfl_xor(zv, 16, 64);
    zv += __shfl_xor(zv, 32, 64);
    if (lane == 0) {
        zpart[blockIdx.x * WPB + wv] = zv;
    }
}

__global__ void finalize_kernel(const float* __restrict__ zpart,
                                float* __restrict__ out) {
    __shared__ float ws4[4];
    int tid = threadIdx.x;   // 256 threads
    float s = 0.0f;
    for (int i = tid; i < ZN; i += 256) s += zpart[i];
    #pragma unroll
    for (int off = 32; off >= 1; off >>= 1) s += __shfl_xor(s, off, 64);
    if ((tid & 63) == 0) ws4[tid >> 6] = s;
    __syncthreads();
    if (tid == 0) {
        float total = ws4[0] + ws4[1] + ws4[2] + ws4[3];
        out[NROWS * NEXP + NROWS * 2] = total * (1.0f / (float)NROWS);
    }
}

extern "C" void kernel_launch(void* const* d_in, const int* in_sizes, int n_in,
                              void* d_out, int out_size, void* d_ws, size_t ws_size,
                              hipStream_t stream) {
    const float* mh      = (const float*)d_in[0];
    const float* weight  = (const float*)d_in[1];
    const float* sigw    = (const float*)d_in[2];
    const float* bias    = (const float*)d_in[3];
    const float* sigb    = (const float*)d_in[4];
    const float* eps_in  = (const float*)d_in[5];
    const float* eps_out = (const float*)d_in[6];

    float* out      = (float*)d_out;
    float* w_noisy  = (float*)d_ws;
    float* b_noisy  = w_noisy + NEXP * DDIM;     // float idx 32768
    float* zpart    = w_noisy + 32800;           // float idx 32800, 128B-aligned

    prep_kernel<<<(NEXP * DDIM) / 256, 256, 0, stream>>>(
        weight, sigw, bias, sigb, eps_in, eps_out, w_noisy, b_noisy);

    router_kernel<<<RBLOCKS, 256, 0, stream>>>(
        mh, w_noisy, b_noisy, out, out + NROWS * NEXP, zpart);

    finalize_kernel<<<1, 256, 0, stream>>>(zpart, out);
}

// Round 4
// 212.342 us; speedup vs baseline: 1.0747x; 1.0747x over previous
//
#include <hip/hip_runtime.h>
#include <math.h>

#define NROWS 16384   // B*T
#define DDIM  2048
#define NEXP  16
#define RBLOCKS 1024  // router grid: 16 rows/block, 4 blocks/CU, fully resident
#define WPB 4         // waves per 256-thread block
#define ZN (RBLOCKS * WPB)

__device__ __forceinline__ float fnoise(float x) {
    return copysignf(sqrtf(fabsf(x)), x);
}

// async 16B global -> LDS (no VGPR round-trip). LDS dest is wave-uniform
// base + lane*16; caller guarantees lane-contiguous layout.
__device__ __forceinline__ void async_copy16(const float4* g, float4* l) {
    __builtin_amdgcn_global_load_lds(
        (const __attribute__((address_space(1))) void*)g,
        (__attribute__((address_space(3))) void*)l, 16, 0, 0);
}

// ws layout (float idx):
//   [0, 32768)       w_noisy [E][D]
//   [32768, 32784)   b_noisy [E]
//   [32800, 36896)   zpartial [ZN] (one float per wave)

__global__ void prep_kernel(const float* __restrict__ weight,
                            const float* __restrict__ sigma_weight,
                            const float* __restrict__ bias,
                            const float* __restrict__ sigma_bias,
                            const float* __restrict__ eps_in,
                            const float* __restrict__ eps_out,
                            float* __restrict__ w_noisy,
                            float* __restrict__ b_noisy) {
    int idx = blockIdx.x * blockDim.x + threadIdx.x;   // 0 .. E*D-1
    int e = idx >> 11;          // / DDIM
    int d = idx & (DDIM - 1);
    float fi = fnoise(eps_in[d]);
    float fo = fnoise(eps_out[e]);
    w_noisy[idx] = weight[idx] + sigma_weight[idx] * fo * fi;
    if (idx < NEXP) {
        b_noisy[idx] = bias[idx] + sigma_bias[idx] * fnoise(eps_out[idx]);
    }
}

// Block: 256 threads = 4 waves; wave wv owns 4 rows. D split in 8 chunks of
// 256 cols. Per chunk: one barrier; w double-buffered in LDS (2x16 KiB) via
// global_load_lds; x for chunk c+1 prefetched into registers at the top of
// chunk c. Fully unrolled c-loop with parity indexing so SROA keeps acc[] and
// xbuf[] in VGPRs (the R3 lambda-with-array-refs version spilled to scratch:
// 91 MB phantom WRITE_SIZE).
__global__ __launch_bounds__(256, 4) void router_kernel(
        const float* __restrict__ x,        // [NROWS][DDIM]
        const float* __restrict__ w_noisy,  // [E][D]
        const float* __restrict__ b_noisy,  // [E]
        float* __restrict__ out_router,     // [NROWS][E]
        float* __restrict__ out_idx,        // [NROWS][2] stored as float
        float* __restrict__ zpart) {        // [ZN]
    __shared__ float4 wlds[2][NEXP * 64];   // 2 x 16 KiB chunks, [16][64] float4

    const int tid  = threadIdx.x;
    const int wv   = tid >> 6;
    const int lane = tid & 63;

    const int rowBase = blockIdx.x * 16 + wv * 4;
    const float4* xr0 = (const float4*)(x + (size_t)(rowBase + 0) * DDIM);
    const float4* xr1 = (const float4*)(x + (size_t)(rowBase + 1) * DDIM);
    const float4* xr2 = (const float4*)(x + (size_t)(rowBase + 2) * DDIM);
    const float4* xr3 = (const float4*)(x + (size_t)(rowBase + 3) * DDIM);
    const float4* wsrc = (const float4*)w_noisy;  // [16][512] float4

    float acc[64];
    #pragma unroll
    for (int i = 0; i < 64; ++i) acc[i] = 0.0f;

    float4 xbuf[2][4];

    // ---- prologue: w chunk 0 -> wlds[0] (async), x chunk 0 -> xbuf[0]
    #pragma unroll
    for (int j = 0; j < 4; ++j) {
        int e = j * 4 + wv;
        async_copy16(wsrc + (size_t)e * 512 + lane,
                     &wlds[0][j * 256 + wv * 64]);
    }
    xbuf[0][0] = xr0[lane];
    xbuf[0][1] = xr1[lane];
    xbuf[0][2] = xr2[lane];
    xbuf[0][3] = xr3[lane];
    __syncthreads();   // implicit vmcnt(0) drain: w0 in LDS, x0 landed

    #pragma unroll
    for (int c = 0; c < 8; ++c) {
        const int cur = c & 1;
        const int nxt = cur ^ 1;
        if (c < 7) {
            // issue x prefetch for chunk c+1 (consumed next iteration)
            int p = (c + 1) * 64 + lane;
            xbuf[nxt][0] = xr0[p];
            xbuf[nxt][1] = xr1[p];
            xbuf[nxt][2] = xr2[p];
            xbuf[nxt][3] = xr3[p];
            // issue async w staging for chunk c+1 into the other LDS buffer
            #pragma unroll
            for (int j = 0; j < 4; ++j) {
                int e = j * 4 + wv;
                async_copy16(wsrc + (size_t)e * 512 + (c + 1) * 64 + lane,
                             &wlds[nxt][j * 256 + wv * 64]);
            }
        }
        #pragma unroll
        for (int e = 0; e < 16; ++e) {
            float4 w = wlds[cur][e * 64 + lane];
            float s0 = acc[0 * 16 + e];
            float s1 = acc[1 * 16 + e];
            float s2 = acc[2 * 16 + e];
            float s3 = acc[3 * 16 + e];
            s0 = fmaf(xbuf[cur][0].x, w.x, s0); s0 = fmaf(xbuf[cur][0].y, w.y, s0);
            s0 = fmaf(xbuf[cur][0].z, w.z, s0); s0 = fmaf(xbuf[cur][0].w, w.w, s0);
            s1 = fmaf(xbuf[cur][1].x, w.x, s1); s1 = fmaf(xbuf[cur][1].y, w.y, s1);
            s1 = fmaf(xbuf[cur][1].z, w.z, s1); s1 = fmaf(xbuf[cur][1].w, w.w, s1);
            s2 = fmaf(xbuf[cur][2].x, w.x, s2); s2 = fmaf(xbuf[cur][2].y, w.y, s2);
            s2 = fmaf(xbuf[cur][2].z, w.z, s2); s2 = fmaf(xbuf[cur][2].w, w.w, s2);
            s3 = fmaf(xbuf[cur][3].x, w.x, s3); s3 = fmaf(xbuf[cur][3].y, w.y, s3);
            s3 = fmaf(xbuf[cur][3].z, w.z, s3); s3 = fmaf(xbuf[cur][3].w, w.w, s3);
            acc[0 * 16 + e] = s0;
            acc[1 * 16 + e] = s1;
            acc[2 * 16 + e] = s2;
            acc[3 * 16 + e] = s3;
        }
        if (c < 7) __syncthreads();   // w(c+1) landed, all waves done with cur
    }

    // Butterfly transpose-reduce: lane l ends with full sum of index l
    // (l = r*16 + e over this wave's 4 rows x 16 experts).
    #pragma unroll
    for (int half = 32; half >= 1; half >>= 1) {
        #pragma unroll
        for (int i = 0; i < half; ++i) {
            bool hi = (lane & half) != 0;
            float keep = hi ? acc[i + half] : acc[i];
            float send = hi ? acc[i] : acc[i + half];
            float recv = __shfl_xor(send, half, 64);
            acc[i] = keep + recv;
        }
    }

    const int e = lane & 15;           // expert owned by this lane
    const int r = lane >> 4;           // local row 0..3
    const int row = rowBase + r;
    float logit = acc[0] + b_noisy[e];

    // top-1 with lower-index tie-break within the 16-lane group
    float m1 = logit; int i1 = e;
    #pragma unroll
    for (int off = 8; off >= 1; off >>= 1) {
        float om = __shfl_xor(m1, off, 64);
        int   oi = __shfl_xor(i1, off, 64);
        if (om > m1 || (om == m1 && oi < i1)) { m1 = om; i1 = oi; }
    }
    // top-2: mask out i1
    float v2 = (e == i1) ? -3.4e38f : logit;
    float m2 = v2; int i2 = e;
    #pragma unroll
    for (int off = 8; off >= 1; off >>= 1) {
        float om = __shfl_xor(m2, off, 64);
        int   oi = __shfl_xor(i2, off, 64);
        if (om > m2 || (om == m2 && oi < i2)) { m2 = om; i2 = oi; }
    }

    // softmax over sparse logits: exp(-1e30 - m1) == 0 exactly, so only
    // positions i1, i2 are nonzero.
    float t = expf(m2 - m1);
    float p1 = 1.0f / (1.0f + t);
    float val = (e == i1) ? p1 : ((e == i2) ? t * p1 : 0.0f);
    out_router[(size_t)rowBase * NEXP + lane] = val;   // fully coalesced

    if (e < 2) {
        out_idx[(size_t)row * 2 + e] = (float)((e == 0) ? i1 : i2);
    }

    // z-loss partial: sum lse^2 over this wave's 4 rows, no atomics.
    float zv = 0.0f;
    if (e == 0) {
        float lse = m1 + log1pf(t);
        zv = lse * lse;
    }
    zv += __shfl_xor(zv, 16, 64);
    zv += __shfl_xor(zv, 32, 64);
    if (lane == 0) {
        zpart[blockIdx.x * WPB + wv] = zv;
    }
}

__global__ void finalize_kernel(const float* __restrict__ zpart,
                                float* __restrict__ out) {
    __shared__ float ws4[4];
    int tid = threadIdx.x;   // 256 threads
    float s = 0.0f;
    for (int i = tid; i < ZN; i += 256) s += zpart[i];
    #pragma unroll
    for (int off = 32; off >= 1; off >>= 1) s += __shfl_xor(s, off, 64);
    if ((tid & 63) == 0) ws4[tid >> 6] = s;
    __syncthreads();
    if (tid == 0) {
        float total = ws4[0] + ws4[1] + ws4[2] + ws4[3];
        out[NROWS * NEXP + NROWS * 2] = total * (1.0f / (float)NROWS);
    }
}

extern "C" void kernel_launch(void* const* d_in, const int* in_sizes, int n_in,
                              void* d_out, int out_size, void* d_ws, size_t ws_size,
                              hipStream_t stream) {
    const float* mh      = (const float*)d_in[0];
    const float* weight  = (const float*)d_in[1];
    const float* sigw    = (const float*)d_in[2];
    const float* bias    = (const float*)d_in[3];
    const float* sigb    = (const float*)d_in[4];
    const float* eps_in  = (const float*)d_in[5];
    const float* eps_out = (const float*)d_in[6];

    float* out      = (float*)d_out;
    float* w_noisy  = (float*)d_ws;
    float* b_noisy  = w_noisy + NEXP * DDIM;     // float idx 32768
    float* zpart    = w_noisy + 32800;           // float idx 32800, 128B-aligned

    prep_kernel<<<(NEXP * DDIM) / 256, 256, 0, stream>>>(
        weight, sigw, bias, sigb, eps_in, eps_out, w_noisy, b_noisy);

    router_kernel<<<RBLOCKS, 256, 0, stream>>>(
        mh, w_noisy, b_noisy, out, out + NROWS * NEXP, zpart);

    finalize_kernel<<<1, 256, 0, stream>>>(zpart, out);
}

// Round 5
// 209.559 us; speedup vs baseline: 1.0890x; 1.0133x over previous
//
#include <hip/hip_runtime.h>
#include <math.h>

#define NROWS 16384   // B*T
#define DDIM  2048
#define NEXP  16
#define RBLOCKS 512   // router grid: 32 rows/block, 2 blocks/CU, fully resident
#define WPB 8         // waves per 512-thread block
#define ZN (RBLOCKS * WPB)

__device__ __forceinline__ float fnoise(float x) {
    return copysignf(sqrtf(fabsf(x)), x);
}

// async 16B global -> LDS (no VGPR round-trip). Pass the wave-uniform LDS
// base; HW adds lane*16. Source pointer includes +lane.
__device__ __forceinline__ void async_copy16(const float4* g, float4* l) {
    __builtin_amdgcn_global_load_lds(
        (const __attribute__((address_space(1))) void*)g,
        (__attribute__((address_space(3))) void*)l, 16, 0, 0);
}

// ws layout (float idx):
//   [0, 32768)       w_noisy [E][D]
//   [32768, 32784)   b_noisy [E]
//   [32800, 36896)   zpartial [ZN] (one float per wave)

__global__ void prep_kernel(const float* __restrict__ weight,
                            const float* __restrict__ sigma_weight,
                            const float* __restrict__ bias,
                            const float* __restrict__ sigma_bias,
                            const float* __restrict__ eps_in,
                            const float* __restrict__ eps_out,
                            float* __restrict__ w_noisy,
                            float* __restrict__ b_noisy) {
    int idx = blockIdx.x * blockDim.x + threadIdx.x;   // 0 .. E*D-1
    int e = idx >> 11;          // / DDIM
    int d = idx & (DDIM - 1);
    float fi = fnoise(eps_in[d]);
    float fo = fnoise(eps_out[e]);
    w_noisy[idx] = weight[idx] + sigma_weight[idx] * fo * fi;
    if (idx < NEXP) {
        b_noisy[idx] = bias[idx] + sigma_bias[idx] * fnoise(eps_out[idx]);
    }
}

// Block: 512 threads = 8 waves; wave wv owns 4 rows. D split in 8 chunks of
// 256 cols, grouped in 4 quarters of 512 cols. w double-buffered in LDS at
// quarter granularity (2 x 32 KiB): stage q+1 right after the quarter-q
// barrier (other buffer -> no hazard), compute 2 chunks (512 FMAs/wave)
// barrier-free, one barrier per quarter = 4 barriers/block total (R4 had 8).
// x prefetched one chunk ahead in registers. 2 blocks/CU co-resident.
__global__ __launch_bounds__(512, 4) void router_kernel(
        const float* __restrict__ x,        // [NROWS][DDIM]
        const float* __restrict__ w_noisy,  // [E][D]
        const float* __restrict__ b_noisy,  // [E]
        float* __restrict__ out_router,     // [NROWS][E]
        float* __restrict__ out_idx,        // [NROWS][2] stored as float
        float* __restrict__ zpart) {        // [ZN]
    __shared__ float4 wlds[2][NEXP * 128];  // 2 x 32 KiB quarters, [16][128] float4

    const int tid  = threadIdx.x;
    const int wv   = tid >> 6;
    const int lane = tid & 63;

    const int rowBase = blockIdx.x * 32 + wv * 4;
    const float4* xr0 = (const float4*)(x + (size_t)(rowBase + 0) * DDIM);
    const float4* xr1 = (const float4*)(x + (size_t)(rowBase + 1) * DDIM);
    const float4* xr2 = (const float4*)(x + (size_t)(rowBase + 2) * DDIM);
    const float4* xr3 = (const float4*)(x + (size_t)(rowBase + 3) * DDIM);
    const float4* wsrc = (const float4*)w_noisy;  // [16][512] float4

    float acc[64];
    #pragma unroll
    for (int i = 0; i < 64; ++i) acc[i] = 0.0f;

    float4 xbuf[2][4];

    // ---- prologue: stage quarter 0 -> wlds[0] (16x128 float4, 4/thread)
    // flat float4 idx fb+lane, fb = j*512 + wv*64 (wave-uniform);
    // expert e = fb>>7 (constant across the wave's 64 lanes since fb%64==0),
    // col = (fb&127)+lane; src = wsrc[e*512 + q*128 + col].
    #pragma unroll
    for (int j = 0; j < 4; ++j) {
        int fb = j * 512 + wv * 64;
        async_copy16(wsrc + (size_t)(fb >> 7) * 512 + (fb & 127) + lane,
                     &wlds[0][fb]);
    }
    xbuf[0][0] = xr0[lane];
    xbuf[0][1] = xr1[lane];
    xbuf[0][2] = xr2[lane];
    xbuf[0][3] = xr3[lane];
    __syncthreads();   // quarter 0 in LDS (vmcnt(0) drain), x0 landed

    #pragma unroll
    for (int q = 0; q < 4; ++q) {
        const int cb = q & 1;
        const int nb = cb ^ 1;
        if (q < 3) {
            // stage quarter q+1 into the other buffer; latency covered by
            // the 512 FMAs/wave below, landed at the end-of-quarter barrier
            #pragma unroll
            for (int j = 0; j < 4; ++j) {
                int fb = j * 512 + wv * 64;
                async_copy16(wsrc + (size_t)(fb >> 7) * 512 + (q + 1) * 128
                                 + (fb & 127) + lane,
                             &wlds[nb][fb]);
            }
        }
        #pragma unroll
        for (int h = 0; h < 2; ++h) {       // chunk c = 2q + h
            const int c = 2 * q + h;
            const int xc = c & 1;
            const int xn = xc ^ 1;
            if (c < 7) {
                // x prefetch for chunk c+1 (consumed next chunk)
                int p = (c + 1) * 64 + lane;
                xbuf[xn][0] = xr0[p];
                xbuf[xn][1] = xr1[p];
                xbuf[xn][2] = xr2[p];
                xbuf[xn][3] = xr3[p];
            }
            #pragma unroll
            for (int e = 0; e < 16; ++e) {
                float4 w = wlds[cb][e * 128 + h * 64 + lane];
                float s0 = acc[0 * 16 + e];
                float s1 = acc[1 * 16 + e];
                float s2 = acc[2 * 16 + e];
                float s3 = acc[3 * 16 + e];
                s0 = fmaf(xbuf[xc][0].x, w.x, s0); s0 = fmaf(xbuf[xc][0].y, w.y, s0);
                s0 = fmaf(xbuf[xc][0].z, w.z, s0); s0 = fmaf(xbuf[xc][0].w, w.w, s0);
                s1 = fmaf(xbuf[xc][1].x, w.x, s1); s1 = fmaf(xbuf[xc][1].y, w.y, s1);
                s1 = fmaf(xbuf[xc][1].z, w.z, s1); s1 = fmaf(xbuf[xc][1].w, w.w, s1);
                s2 = fmaf(xbuf[xc][2].x, w.x, s2); s2 = fmaf(xbuf[xc][2].y, w.y, s2);
                s2 = fmaf(xbuf[xc][2].z, w.z, s2); s2 = fmaf(xbuf[xc][2].w, w.w, s2);
                s3 = fmaf(xbuf[xc][3].x, w.x, s3); s3 = fmaf(xbuf[xc][3].y, w.y, s3);
                s3 = fmaf(xbuf[xc][3].z, w.z, s3); s3 = fmaf(xbuf[xc][3].w, w.w, s3);
                acc[0 * 16 + e] = s0;
                acc[1 * 16 + e] = s1;
                acc[2 * 16 + e] = s2;
                acc[3 * 16 + e] = s3;
            }
        }
        if (q < 3) __syncthreads();   // q+1 landed; all waves done with q
    }

    // Butterfly transpose-reduce: lane l ends with full sum of index l
    // (l = r*16 + e over this wave's 4 rows x 16 experts).
    #pragma unroll
    for (int half = 32; half >= 1; half >>= 1) {
        #pragma unroll
        for (int i = 0; i < half; ++i) {
            bool hi = (lane & half) != 0;
            float keep = hi ? acc[i + half] : acc[i];
            float send = hi ? acc[i] : acc[i + half];
            float recv = __shfl_xor(send, half, 64);
            acc[i] = keep + recv;
        }
    }

    const int e = lane & 15;           // expert owned by this lane
    const int r = lane >> 4;           // local row 0..3
    const int row = rowBase + r;
    float logit = acc[0] + b_noisy[e];

    // top-1 with lower-index tie-break within the 16-lane group
    float m1 = logit; int i1 = e;
    #pragma unroll
    for (int off = 8; off >= 1; off >>= 1) {
        float om = __shfl_xor(m1, off, 64);
        int   oi = __shfl_xor(i1, off, 64);
        if (om > m1 || (om == m1 && oi < i1)) { m1 = om; i1 = oi; }
    }
    // top-2: mask out i1
    float v2 = (e == i1) ? -3.4e38f : logit;
    float m2 = v2; int i2 = e;
    #pragma unroll
    for (int off = 8; off >= 1; off >>= 1) {
        float om = __shfl_xor(m2, off, 64);
        int   oi = __shfl_xor(i2, off, 64);
        if (om > m2 || (om == m2 && oi < i2)) { m2 = om; i2 = oi; }
    }

    // softmax over sparse logits: exp(-1e30 - m1) == 0 exactly, so only
    // positions i1, i2 are nonzero.
    float t = expf(m2 - m1);
    float p1 = 1.0f / (1.0f + t);
    float val = (e == i1) ? p1 : ((e == i2) ? t * p1 : 0.0f);
    out_router[(size_t)rowBase * NEXP + lane] = val;   // fully coalesced

    if (e < 2) {
        out_idx[(size_t)row * 2 + e] = (float)((e == 0) ? i1 : i2);
    }

    // z-loss partial: sum lse^2 over this wave's 4 rows, no atomics.
    float zv = 0.0f;
    if (e == 0) {
        float lse = m1 + log1pf(t);
        zv = lse * lse;
    }
    zv += __shfl_xor(zv, 16, 64);
    zv += __shfl_xor(zv, 32, 64);
    if (lane == 0) {
        zpart[blockIdx.x * WPB + wv] = zv;
    }
}

__global__ void finalize_kernel(const float* __restrict__ zpart,
                                float* __restrict__ out) {
    __shared__ float ws4[4];
    int tid = threadIdx.x;   // 256 threads
    float s = 0.0f;
    for (int i = tid; i < ZN; i += 256) s += zpart[i];
    #pragma unroll
    for (int off = 32; off >= 1; off >>= 1) s += __shfl_xor(s, off, 64);
    if ((tid & 63) == 0) ws4[tid >> 6] = s;
    __syncthreads();
    if (tid == 0) {
        float total = ws4[0] + ws4[1] + ws4[2] + ws4[3];
        out[NROWS * NEXP + NROWS * 2] = total * (1.0f / (float)NROWS);
    }
}

extern "C" void kernel_launch(void* const* d_in, const int* in_sizes, int n_in,
                              void* d_out, int out_size, void* d_ws, size_t ws_size,
                              hipStream_t stream) {
    const float* mh      = (const float*)d_in[0];
    const float* weight  = (const float*)d_in[1];
    const float* sigw    = (const float*)d_in[2];
    const float* bias    = (const float*)d_in[3];
    const float* sigb    = (const float*)d_in[4];
    const float* eps_in  = (const float*)d_in[5];
    const float* eps_out = (const float*)d_in[6];

    float* out      = (float*)d_out;
    float* w_noisy  = (float*)d_ws;
    float* b_noisy  = w_noisy + NEXP * DDIM;     // float idx 32768
    float* zpart    = w_noisy + 32800;           // float idx 32800, 128B-aligned

    prep_kernel<<<(NEXP * DDIM) / 256, 256, 0, stream>>>(
        weight, sigw, bias, sigb, eps_in, eps_out, w_noisy, b_noisy);

    router_kernel<<<RBLOCKS, 512, 0, stream>>>(
        mh, w_noisy, b_noisy, out, out + NROWS * NEXP, zpart);

    finalize_kernel<<<1, 256, 0, stream>>>(zpart, out);
}